// Round 7
// baseline (921.398 us; speedup 1.0000x reference)
//
#include <hip/hip_runtime.h>

#define NN 40960
#define NE 655360
#define ET (NE + NN)        // 696320 edges incl self-loops
#define D 128
#define NG 16
#define PL 33280            // params per layer: WF[32768], bf[256], att[128], b[128]

typedef unsigned int u32;
typedef unsigned short u16;
typedef long long i64;

__device__ __forceinline__ float bf2f(u16 v){ return __uint_as_float(((u32)v)<<16); }
__device__ __forceinline__ u16 f2bf(float f){
  u32 u = __float_as_uint(f);
  return (u16)((u + 0x7FFFu + ((u>>16)&1u)) >> 16);
}
__device__ __forceinline__ int geti(const void* p, long long i, int f64, int bound){
  long long v = f64 ? ((const i64*)p)[i] : (long long)((const int*)p)[i];
  int x = (int)v;
  return (x < 0) ? 0 : ((x >= bound) ? bound-1 : x);
}
__device__ __forceinline__ void stf(void* p, long long i, float v, int isbf){
  if (isbf) ((u16*)p)[i] = f2bf(v); else ((float*)p)[i] = v;
}
__device__ __forceinline__ float rdf(const void* p, int i, int isbf){
  return isbf ? bf2f(((const u16*)p)[i]) : ((const float*)p)[i];
}

__global__ void k_zero_out32(float* __restrict__ o, int n){
  int i = blockIdx.x*256 + threadIdx.x;
  if (i < n) o[i] = 0.f;
}
__global__ void k_zero_u32(u32* __restrict__ o, int n){
  int i = blockIdx.x*256 + threadIdx.x;
  if (i < n) o[i] = 0u;
}

// flags[0]: indices are int64 ; flags[1]: floats are bf16
__global__ void k_detect(const void* __restrict__ ei, const void* __restrict__ x, int* __restrict__ flags){
  __shared__ int nz, cnt;
  if (threadIdx.x == 0){ nz = 0; cnt = 0; }
  __syncthreads();
  if (((const int*)ei)[2*threadIdx.x + 1] != 0) atomicAdd(&nz, 1);
  if (threadIdx.x < 128){
    u16 v = ((const u16*)x)[2*threadIdx.x];
    int ex = (v >> 7) & 0xFF;
    if (ex >= 100 && ex <= 140) atomicAdd(&cnt, 1);
  }
  __syncthreads();
  if (threadIdx.x == 0){
    flags[0] = (nz == 0) ? 1 : 0;
    flags[1] = (cnt >= 64) ? 1 : 0;
  }
}

__global__ void k_cvt(const void* __restrict__ src, float* __restrict__ dst, int n, const int* __restrict__ flags){
  int i = blockIdx.x*256 + threadIdx.x;
  if (i >= n) return;
  dst[i] = rdf(src, i, flags[1]);
}

// fused param pack: WF[k*256+gc] = (gc<128 ? Wl[k][gc] : Wr[k][gc-128]); bf[256]=bl|br; att; b
__global__ void k_cvtp(const void* Wl, const void* bl, const void* Wr, const void* br,
                       const void* att, const void* b, float* __restrict__ p, const int* __restrict__ flags){
  int i = blockIdx.x*256 + threadIdx.x;
  if (i >= PL) return;
  int isbf = flags[1];
  float v;
  if (i < 32768){
    int k = i >> 8, gc = i & 255;
    v = (gc < 128) ? rdf(Wl, k*128 + gc, isbf) : rdf(Wr, k*128 + gc - 128, isbf);
  }
  else if (i < 33024){ int gc = i - 32768; v = (gc < 128) ? rdf(bl, gc, isbf) : rdf(br, gc - 128, isbf); }
  else if (i < 33152) v = rdf(att, i - 33024, isbf);
  else                v = rdf(b, i - 33152, isbf);
  p[i] = v;
}

// ---------- CSR build (by dst, self-loops appended); entry packs src|dst<<16 ----------
__global__ void k_hist(const void* __restrict__ ei, u32* __restrict__ cursor, const int* __restrict__ flags){
  int e = blockIdx.x*256 + threadIdx.x;
  if (e >= ET) return;
  int dd = (e < NE) ? geti(ei, (long long)NE + e, flags[0], NN) : e - NE;
  atomicAdd(&cursor[dd], 1u);
}

__global__ __launch_bounds__(1024) void k_scan(u32* __restrict__ cursor, u32* __restrict__ offs){
  __shared__ u32 part[1024];
  int t = threadIdx.x;
  int base = t * 40;
  u32 s = 0;
  #pragma unroll 4
  for (int i = 0; i < 40; ++i) s += cursor[base + i];
  part[t] = s;
  __syncthreads();
  for (int off = 1; off < 1024; off <<= 1){
    u32 v = (t >= off) ? part[t - off] : 0u;
    __syncthreads();
    part[t] += v;
    __syncthreads();
  }
  u32 run = (t == 0) ? 0u : part[t - 1];
  for (int i = 0; i < 40; ++i){
    u32 d = cursor[base + i];
    offs[base + i] = run;
    cursor[base + i] = run;
    run += d;
  }
  if (t == 1023) offs[NN] = run;
}

__global__ void k_scatter(const void* __restrict__ ei, u32* __restrict__ cursor,
                          u32* __restrict__ csr, const int* __restrict__ flags){
  int e = blockIdx.x*256 + threadIdx.x;
  if (e >= ET) return;
  int f = flags[0];
  int s, dd;
  if (e < NE){ s = geti(ei, e, f, NN); dd = geti(ei, (long long)NE + e, f, NN); }
  else { s = dd = e - NE; }
  u32 pos = atomicAdd(&cursor[dd], 1u);
  csr[pos] = (u32)s | ((u32)dd << 16);
}

__global__ void k_bounds(const void* __restrict__ batch, u32* __restrict__ bnd, const int* __restrict__ flags){
  int g = threadIdx.x;
  if (g > NG) return;
  if (g == NG){ bnd[NG] = NN; return; }
  int f = flags[0];
  int lo = 0, hi = NN;
  while (lo < hi){
    int mid = (lo + hi) >> 1;
    if (geti(batch, mid, f, NG) < g) lo = mid + 1; else hi = mid;
  }
  bnd[g] = (u32)lo;
}

// ---------- GEMM: 64 rows x 64 cols per block, K=128 one-shot, 4x4 register tile ----------
__global__ __launch_bounds__(256) void k_gemm(const float* __restrict__ X, const float* __restrict__ pr,
                                              float* __restrict__ xl, float* __restrict__ xr)
{
  __shared__ float Xs[128][64];
  __shared__ float Ws[128][64];
  int tid = threadIdx.x;
  int row0 = blockIdx.x * 64;
  int bc0  = blockIdx.y * 64;

  const float4* Xg = (const float4*)(X + (size_t)row0 * D);
  #pragma unroll
  for (int i = 0; i < 8; ++i){
    int idx = tid + i*256;
    int row = idx >> 5, k4 = idx & 31;
    float4 v = Xg[(size_t)row*32 + k4];
    Xs[k4*4+0][row] = v.x;
    Xs[k4*4+1][row] = v.y;
    Xs[k4*4+2][row] = v.z;
    Xs[k4*4+3][row] = v.w;
  }
  #pragma unroll
  for (int i = 0; i < 8; ++i){
    int idx = tid + i*256;
    int k = idx >> 4, c4 = idx & 15;
    float4 v = *(const float4*)(pr + (size_t)k*256 + bc0 + c4*4);
    *(float4*)&Ws[k][c4*4] = v;
  }
  __syncthreads();

  int ty = tid >> 4, tx = tid & 15;
  int r = ty*4, c = tx*4;
  float4 bias = *(const float4*)(pr + 32768 + bc0 + c);
  float acc[4][4];
  #pragma unroll
  for (int i = 0; i < 4; ++i){
    acc[i][0] = bias.x; acc[i][1] = bias.y; acc[i][2] = bias.z; acc[i][3] = bias.w;
  }
  #pragma unroll 4
  for (int k = 0; k < 128; ++k){
    float4 a = *(const float4*)&Xs[k][r];
    float4 b = *(const float4*)&Ws[k][c];
    acc[0][0] = fmaf(a.x, b.x, acc[0][0]); acc[0][1] = fmaf(a.x, b.y, acc[0][1]);
    acc[0][2] = fmaf(a.x, b.z, acc[0][2]); acc[0][3] = fmaf(a.x, b.w, acc[0][3]);
    acc[1][0] = fmaf(a.y, b.x, acc[1][0]); acc[1][1] = fmaf(a.y, b.y, acc[1][1]);
    acc[1][2] = fmaf(a.y, b.z, acc[1][2]); acc[1][3] = fmaf(a.y, b.w, acc[1][3]);
    acc[2][0] = fmaf(a.z, b.x, acc[2][0]); acc[2][1] = fmaf(a.z, b.y, acc[2][1]);
    acc[2][2] = fmaf(a.z, b.z, acc[2][2]); acc[2][3] = fmaf(a.z, b.w, acc[2][3]);
    acc[3][0] = fmaf(a.w, b.x, acc[3][0]); acc[3][1] = fmaf(a.w, b.y, acc[3][1]);
    acc[3][2] = fmaf(a.w, b.z, acc[3][2]); acc[3][3] = fmaf(a.w, b.w, acc[3][3]);
  }
  float* base = (bc0 < 128) ? xl : xr;
  int co = (bc0 < 128) ? bc0 + c : bc0 - 128 + c;
  #pragma unroll
  for (int i = 0; i < 4; ++i)
    *(float4*)(base + (size_t)(row0 + r + i)*D + co) =
        make_float4(acc[i][0], acc[i][1], acc[i][2], acc[i][3]);
}

// ---------- E1: thread-per-edge logits, all 4 heads in-register, no cross-lane ----------
__global__ __launch_bounds__(256) void k_logit(const float* __restrict__ xl, const float* __restrict__ xr,
    const u32* __restrict__ csr, const float* __restrict__ pr, float4* __restrict__ e4)
{
  int j = blockIdx.x*256 + threadIdx.x;
  if (j >= ET) return;
  u32 v = csr[j];
  int s = v & 0xFFFF, d = v >> 16;
  const float4* A = (const float4*)(xl + (size_t)s*D);
  const float4* B = (const float4*)(xr + (size_t)d*D);
  const float* att = pr + 33024;
  float h0 = 0.f, h1 = 0.f, h2 = 0.f, h3 = 0.f;
  #pragma unroll
  for (int u = 0; u < 32; ++u){           // 4 channels per iter; head = u>>3 (static)
    float4 a = A[u], b = B[u];
    int ch = u*4;
    float m, p = 0.f;
    m = a.x + b.x; m = (m > 0.f) ? m : 0.2f*m; p = fmaf(m, att[ch+0], p);
    m = a.y + b.y; m = (m > 0.f) ? m : 0.2f*m; p = fmaf(m, att[ch+1], p);
    m = a.z + b.z; m = (m > 0.f) ? m : 0.2f*m; p = fmaf(m, att[ch+2], p);
    m = a.w + b.w; m = (m > 0.f) ? m : 0.2f*m; p = fmaf(m, att[ch+3], p);
    if ((u >> 3) == 0) h0 += p;
    else if ((u >> 3) == 1) h1 += p;
    else if ((u >> 3) == 2) h2 += p;
    else h3 += p;
  }
  e4[j] = make_float4(h0, h1, h2, h3);
}

// ---------- E2: thread-per-node softmax (max, exp once, denom) ----------
__global__ __launch_bounds__(256) void k_soft(const float4* __restrict__ e4, const u32* __restrict__ offs,
                                              float4* __restrict__ ex4, float4* __restrict__ invq)
{
  int n = blockIdx.x*256 + threadIdx.x;
  if (n >= NN) return;
  u32 j0 = offs[n], j1 = offs[n+1];
  float4 mx = make_float4(-1e30f, -1e30f, -1e30f, -1e30f);
  for (u32 j = j0; j < j1; ++j){
    float4 e = e4[j];
    mx.x = fmaxf(mx.x, e.x); mx.y = fmaxf(mx.y, e.y);
    mx.z = fmaxf(mx.z, e.z); mx.w = fmaxf(mx.w, e.w);
  }
  float dx = 0.f, dy = 0.f, dz = 0.f, dw = 0.f;
  for (u32 j = j0; j < j1; ++j){
    float4 e = e4[j];
    float4 ex = make_float4(__expf(e.x - mx.x), __expf(e.y - mx.y),
                            __expf(e.z - mx.z), __expf(e.w - mx.w));
    ex4[j] = ex;
    dx += ex.x; dy += ex.y; dz += ex.z; dw += ex.w;
  }
  invq[n] = make_float4(1.f/dx, 1.f/dy, 1.f/dz, 1.f/dw);  // denom >= 1 (self-loop)
}

// ---------- E3: wave-per-node aggregate, no DS ops, normalization factored out ----------
__global__ __launch_bounds__(256) void k_aggr(const float* __restrict__ xl, const u32* __restrict__ offs,
    const u32* __restrict__ csr, const float4* __restrict__ ex4, const float4* __restrict__ invq,
    const float* __restrict__ pr, float* __restrict__ hnew, void* __restrict__ out,
    const int* __restrict__ flags, int last)
{
  int node = blockIdx.x*4 + (threadIdx.x >> 6);
  int lane = threadIdx.x & 63;
  int c1 = lane, c2 = lane + 64;
  bool lo = lane < 32;
  u32 j0 = offs[node], j1 = offs[node + 1];
  float acc1 = 0.f, acc2 = 0.f;
  for (u32 j = j0; j < j1; ++j){
    int s = (int)(csr[j] & 0xFFFFu);
    float4 ex = ex4[j];                 // broadcast (same addr across lanes)
    float e1 = lo ? ex.x : ex.y;
    float e2 = lo ? ex.z : ex.w;
    acc1 = fmaf(e1, xl[(size_t)s*D + c1], acc1);
    acc2 = fmaf(e2, xl[(size_t)s*D + c2], acc2);
  }
  float4 iv = invq[node];
  float v1 = acc1 * (lo ? iv.x : iv.y) + pr[33152 + c1];
  float v2 = acc2 * (lo ? iv.z : iv.w) + pr[33152 + c2];
  if (!last){
    hnew[(size_t)node*D + c1] = fmaxf(v1, 0.f);
    hnew[(size_t)node*D + c2] = fmaxf(v2, 0.f);
  } else {
    hnew[(size_t)node*D + c1] = v1;
    hnew[(size_t)node*D + c2] = v2;
    int isbf = flags[1];
    stf(out, (long long)NG*D + (long long)node*D + c1, v1, isbf);
    stf(out, (long long)NG*D + (long long)node*D + c2, v2, isbf);
  }
}

// ---------- two-stage mean pool ----------
__global__ __launch_bounds__(256) void k_pool1(const float* __restrict__ h, const u32* __restrict__ bnd,
                                               float* __restrict__ pool){
  int g = blockIdx.x >> 6, sl = blockIdx.x & 63;
  int ch = threadIdx.x & 127, ro = threadIdx.x >> 7;
  u32 b0 = bnd[g], b1 = bnd[g + 1];
  float acc = 0.f;
  for (u32 r = b0 + sl*2 + ro; r < b1; r += 128) acc += h[(size_t)r*D + ch];
  unsafeAtomicAdd(&pool[g*D + ch], acc);
}

__global__ void k_pool2(const float* __restrict__ pool, const u32* __restrict__ bnd,
                        void* __restrict__ out, const int* __restrict__ flags){
  int i = blockIdx.x*256 + threadIdx.x;
  if (i >= NG*D) return;
  int g = i >> 7;
  float c = (float)(bnd[g + 1] - bnd[g]);
  stf(out, i, pool[i] / fmaxf(c, 1.f), flags[1]);
}

extern "C" void kernel_launch(void* const* d_in, const int* in_sizes, int n_in,
                              void* d_out, int out_size, void* d_ws, size_t ws_size,
                              hipStream_t stream) {
  const void* x     = d_in[0];
  const void* ei    = d_in[1];
  const void* batch = d_in[2];

  const long long nf = (long long)NN*D*3 + 3*PL + NG*D;
  const long long nu = (NN + 1) + NN + ET + (NG + 1) + 2;
  if (ws_size < (size_t)(nf + nu)*4 + 256) return;

  float* ws    = (float*)d_ws;
  float* xf    = ws;                               // NN*D (h buffer; scratch between gemm and aggr)
  float* xl    = xf + (size_t)NN*D;
  float* xr    = xl + (size_t)NN*D;
  float* prm   = xr + (size_t)NN*D;                // 3*PL
  float* pool  = prm + 3*PL;                       // NG*D
  u32*  offs   = (u32*)(pool + NG*D);              // NN+1
  u32*  cursor = offs + (NN + 1);                  // NN
  u32*  csr    = cursor + NN;                      // ET
  u32*  bnd    = csr + ET;                         // NG+1
  int*  flags  = (int*)(bnd + (NG + 1));           // 2
  // aliases (lifetime-disjoint):
  float4* e4   = (float4*)xf;                      // ET float4s <= NN*D floats  (xf dead after gemm)
  float4* ex4  = (float4*)xr;                      // ET float4s                 (xr dead after E1)
  float4* invq = ex4 + ET;                         // NN float4s (fits in xr region)

  k_detect<<<1, 256, 0, stream>>>(ei, x, flags);
  k_cvt<<<(NN*D)/256, 256, 0, stream>>>(x, xf, NN*D, flags);
  for (int l = 0; l < 3; ++l)
    k_cvtp<<<(PL + 255)/256, 256, 0, stream>>>(d_in[3+6*l+0], d_in[3+6*l+1], d_in[3+6*l+2],
                                               d_in[3+6*l+3], d_in[3+6*l+4], d_in[3+6*l+5],
                                               prm + (size_t)l*PL, flags);

  k_zero_u32<<<NN/256, 256, 0, stream>>>(cursor, NN);
  k_hist<<<ET/256, 256, 0, stream>>>(ei, cursor, flags);
  k_scan<<<1, 1024, 0, stream>>>(cursor, offs);
  k_scatter<<<ET/256, 256, 0, stream>>>(ei, cursor, csr, flags);
  k_bounds<<<1, 32, 0, stream>>>(batch, bnd, flags);
  k_zero_out32<<<8, 256, 0, stream>>>(pool, NG*D);

  for (int l = 0; l < 3; ++l){
    const float* p = prm + (size_t)l*PL;
    k_gemm<<<dim3(NN/64, 4), 256, 0, stream>>>(xf, p, xl, xr);
    k_logit<<<ET/256, 256, 0, stream>>>(xl, xr, csr, p, e4);
    k_soft<<<NN/256, 256, 0, stream>>>(e4, offs, ex4, invq);
    k_aggr<<<NN/4, 256, 0, stream>>>(xl, offs, csr, ex4, invq, p, xf, d_out, flags, l == 2);
  }
  k_pool1<<<NG*64, 256, 0, stream>>>(xf, bnd, pool);
  k_pool2<<<8, 256, 0, stream>>>(pool, bnd, d_out, flags);
}

// Round 8
// 522.172 us; speedup vs baseline: 1.7645x; 1.7645x over previous
//
#include <hip/hip_runtime.h>

#define NN 40960
#define NE 655360
#define ET (NE + NN)        // 696320 edges incl self-loops
#define D 128
#define NG 16
#define PL 33280            // params per layer: WF[32768], bf[256], att[128], b[128]

typedef unsigned int u32;
typedef unsigned short u16;
typedef long long i64;

__device__ __forceinline__ float bf2f(u16 v){ return __uint_as_float(((u32)v)<<16); }
__device__ __forceinline__ u16 f2bf(float f){
  u32 u = __float_as_uint(f);
  return (u16)((u + 0x7FFFu + ((u>>16)&1u)) >> 16);
}
__device__ __forceinline__ int geti(const void* p, long long i, int f64, int bound){
  long long v = f64 ? ((const i64*)p)[i] : (long long)((const int*)p)[i];
  int x = (int)v;
  return (x < 0) ? 0 : ((x >= bound) ? bound-1 : x);
}
__device__ __forceinline__ void stf(void* p, long long i, float v, int isbf){
  if (isbf) ((u16*)p)[i] = f2bf(v); else ((float*)p)[i] = v;
}
__device__ __forceinline__ float rdf(const void* p, int i, int isbf){
  return isbf ? bf2f(((const u16*)p)[i]) : ((const float*)p)[i];
}

__global__ void k_zero_out32(float* __restrict__ o, int n){
  int i = blockIdx.x*256 + threadIdx.x;
  if (i < n) o[i] = 0.f;
}
__global__ void k_zero_u32(u32* __restrict__ o, int n){
  int i = blockIdx.x*256 + threadIdx.x;
  if (i < n) o[i] = 0u;
}

// flags[0]: indices are int64 ; flags[1]: floats are bf16
__global__ void k_detect(const void* __restrict__ ei, const void* __restrict__ x, int* __restrict__ flags){
  __shared__ int nz, cnt;
  if (threadIdx.x == 0){ nz = 0; cnt = 0; }
  __syncthreads();
  if (((const int*)ei)[2*threadIdx.x + 1] != 0) atomicAdd(&nz, 1);
  if (threadIdx.x < 128){
    u16 v = ((const u16*)x)[2*threadIdx.x];
    int ex = (v >> 7) & 0xFF;
    if (ex >= 100 && ex <= 140) atomicAdd(&cnt, 1);
  }
  __syncthreads();
  if (threadIdx.x == 0){
    flags[0] = (nz == 0) ? 1 : 0;
    flags[1] = (cnt >= 64) ? 1 : 0;
  }
}

__global__ void k_cvt(const void* __restrict__ src, float* __restrict__ dst, int n, const int* __restrict__ flags){
  int i = blockIdx.x*256 + threadIdx.x;
  if (i >= n) return;
  dst[i] = rdf(src, i, flags[1]);
}

// fused param pack: WF[k*256+gc] = (gc<128 ? Wl[k][gc] : Wr[k][gc-128]); bf[256]=bl|br; att; b
__global__ void k_cvtp(const void* Wl, const void* bl, const void* Wr, const void* br,
                       const void* att, const void* b, float* __restrict__ p, const int* __restrict__ flags){
  int i = blockIdx.x*256 + threadIdx.x;
  if (i >= PL) return;
  int isbf = flags[1];
  float v;
  if (i < 32768){
    int k = i >> 8, gc = i & 255;
    v = (gc < 128) ? rdf(Wl, k*128 + gc, isbf) : rdf(Wr, k*128 + gc - 128, isbf);
  }
  else if (i < 33024){ int gc = i - 32768; v = (gc < 128) ? rdf(bl, gc, isbf) : rdf(br, gc - 128, isbf); }
  else if (i < 33152) v = rdf(att, i - 33024, isbf);
  else                v = rdf(b, i - 33152, isbf);
  p[i] = v;
}

// ---------- CSR build (by dst, self-loops appended); entry packs src|dst<<16 ----------
__global__ void k_hist(const void* __restrict__ ei, u32* __restrict__ cursor, const int* __restrict__ flags){
  int e = blockIdx.x*256 + threadIdx.x;
  if (e >= ET) return;
  int dd = (e < NE) ? geti(ei, (long long)NE + e, flags[0], NN) : e - NE;
  atomicAdd(&cursor[dd], 1u);
}

__global__ __launch_bounds__(1024) void k_scan(u32* __restrict__ cursor, u32* __restrict__ offs){
  __shared__ u32 part[1024];
  int t = threadIdx.x;
  int base = t * 40;
  u32 s = 0;
  #pragma unroll 4
  for (int i = 0; i < 40; ++i) s += cursor[base + i];
  part[t] = s;
  __syncthreads();
  for (int off = 1; off < 1024; off <<= 1){
    u32 v = (t >= off) ? part[t - off] : 0u;
    __syncthreads();
    part[t] += v;
    __syncthreads();
  }
  u32 run = (t == 0) ? 0u : part[t - 1];
  for (int i = 0; i < 40; ++i){
    u32 d = cursor[base + i];
    offs[base + i] = run;
    cursor[base + i] = run;
    run += d;
  }
  if (t == 1023) offs[NN] = run;
}

__global__ void k_scatter(const void* __restrict__ ei, u32* __restrict__ cursor,
                          u32* __restrict__ csr, const int* __restrict__ flags){
  int e = blockIdx.x*256 + threadIdx.x;
  if (e >= ET) return;
  int f = flags[0];
  int s, dd;
  if (e < NE){ s = geti(ei, e, f, NN); dd = geti(ei, (long long)NE + e, f, NN); }
  else { s = dd = e - NE; }
  u32 pos = atomicAdd(&cursor[dd], 1u);
  csr[pos] = (u32)s | ((u32)dd << 16);
}

__global__ void k_bounds(const void* __restrict__ batch, u32* __restrict__ bnd, const int* __restrict__ flags){
  int g = threadIdx.x;
  if (g > NG) return;
  if (g == NG){ bnd[NG] = NN; return; }
  int f = flags[0];
  int lo = 0, hi = NN;
  while (lo < hi){
    int mid = (lo + hi) >> 1;
    if (geti(batch, mid, f, NG) < g) lo = mid + 1; else hi = mid;
  }
  bnd[g] = (u32)lo;
}

// ---------- GEMM: 64 rows x 64 cols per block, K=128 one-shot, 4x4 register tile ----------
__global__ __launch_bounds__(256) void k_gemm(const float* __restrict__ X, const float* __restrict__ pr,
                                              float* __restrict__ xl, float* __restrict__ xr)
{
  __shared__ float Xs[128][64];
  __shared__ float Ws[128][64];
  int tid = threadIdx.x;
  int row0 = blockIdx.x * 64;
  int bc0  = blockIdx.y * 64;

  const float4* Xg = (const float4*)(X + (size_t)row0 * D);
  #pragma unroll
  for (int i = 0; i < 8; ++i){
    int idx = tid + i*256;
    int row = idx >> 5, k4 = idx & 31;
    float4 v = Xg[(size_t)row*32 + k4];
    Xs[k4*4+0][row] = v.x;
    Xs[k4*4+1][row] = v.y;
    Xs[k4*4+2][row] = v.z;
    Xs[k4*4+3][row] = v.w;
  }
  #pragma unroll
  for (int i = 0; i < 8; ++i){
    int idx = tid + i*256;
    int k = idx >> 4, c4 = idx & 15;
    float4 v = *(const float4*)(pr + (size_t)k*256 + bc0 + c4*4);
    *(float4*)&Ws[k][c4*4] = v;
  }
  __syncthreads();

  int ty = tid >> 4, tx = tid & 15;
  int r = ty*4, c = tx*4;
  float4 bias = *(const float4*)(pr + 32768 + bc0 + c);
  float acc[4][4];
  #pragma unroll
  for (int i = 0; i < 4; ++i){
    acc[i][0] = bias.x; acc[i][1] = bias.y; acc[i][2] = bias.z; acc[i][3] = bias.w;
  }
  #pragma unroll 4
  for (int k = 0; k < 128; ++k){
    float4 a = *(const float4*)&Xs[k][r];
    float4 b = *(const float4*)&Ws[k][c];
    acc[0][0] = fmaf(a.x, b.x, acc[0][0]); acc[0][1] = fmaf(a.x, b.y, acc[0][1]);
    acc[0][2] = fmaf(a.x, b.z, acc[0][2]); acc[0][3] = fmaf(a.x, b.w, acc[0][3]);
    acc[1][0] = fmaf(a.y, b.x, acc[1][0]); acc[1][1] = fmaf(a.y, b.y, acc[1][1]);
    acc[1][2] = fmaf(a.y, b.z, acc[1][2]); acc[1][3] = fmaf(a.y, b.w, acc[1][3]);
    acc[2][0] = fmaf(a.z, b.x, acc[2][0]); acc[2][1] = fmaf(a.z, b.y, acc[2][1]);
    acc[2][2] = fmaf(a.z, b.z, acc[2][2]); acc[2][3] = fmaf(a.z, b.w, acc[2][3]);
    acc[3][0] = fmaf(a.w, b.x, acc[3][0]); acc[3][1] = fmaf(a.w, b.y, acc[3][1]);
    acc[3][2] = fmaf(a.w, b.z, acc[3][2]); acc[3][3] = fmaf(a.w, b.w, acc[3][3]);
  }
  float* base = (bc0 < 128) ? xl : xr;
  int co = (bc0 < 128) ? bc0 + c : bc0 - 128 + c;
  #pragma unroll
  for (int i = 0; i < 4; ++i)
    *(float4*)(base + (size_t)(row0 + r + i)*D + co) =
        make_float4(acc[i][0], acc[i][1], acc[i][2], acc[i][3]);
}

// ---------- fused per-node attention: wave per node, 2 edges/iter, 4 ch/lane ----------
// lane l (of 64): half = l>>5, l32 = l&31, channels c = l32*4 .. +3, head = l32>>3.
// Per edge: coalesced float4 gather of xl row; logit via 3-level xor-butterfly over the
// 8 lanes sharing a head; online softmax per half-wave; halves merged at the end.
__global__ __launch_bounds__(256) void k_node(const float* __restrict__ xl, const float* __restrict__ xr,
    const u32* __restrict__ offs, const u32* __restrict__ csr, const float* __restrict__ pr,
    float* __restrict__ hnew, void* __restrict__ out, const int* __restrict__ flags, int last)
{
  int node = blockIdx.x*4 + (threadIdx.x >> 6);
  int lane = threadIdx.x & 63;
  int half = lane >> 5;
  int c = (lane & 31) * 4;
  float4 xrv  = *(const float4*)(xr + (size_t)node*D + c);
  float4 attv = *(const float4*)(pr + 33024 + c);
  u32 j0 = offs[node], j1 = offs[node + 1];

  float mx = -1e30f, ssum = 0.f;
  float4 acc = make_float4(0.f, 0.f, 0.f, 0.f);
  for (u32 j = j0 + half; j < j1; j += 2){
    int s = (int)(csr[j] & 0xFFFFu);
    float4 g = *(const float4*)(xl + (size_t)s*D + c);
    float m, p;
    m = g.x + xrv.x; m = (m > 0.f) ? m : 0.2f*m; p  = m * attv.x;
    m = g.y + xrv.y; m = (m > 0.f) ? m : 0.2f*m; p  = fmaf(m, attv.y, p);
    m = g.z + xrv.z; m = (m > 0.f) ? m : 0.2f*m; p  = fmaf(m, attv.z, p);
    m = g.w + xrv.w; m = (m > 0.f) ? m : 0.2f*m; p  = fmaf(m, attv.w, p);
    p += __shfl_xor(p, 1, 64);
    p += __shfl_xor(p, 2, 64);
    p += __shfl_xor(p, 4, 64);     // all 8 head-lanes now hold the logit
    float n  = fmaxf(mx, p);
    float eo = __expf(mx - n), en = __expf(p - n);
    ssum  = fmaf(ssum, eo, en);
    acc.x = fmaf(acc.x, eo, en * g.x);
    acc.y = fmaf(acc.y, eo, en * g.y);
    acc.z = fmaf(acc.z, eo, en * g.z);
    acc.w = fmaf(acc.w, eo, en * g.w);
    mx = n;
  }
  // merge the two half-wave online-softmax states (lanes l and l+32 share channels)
  float mo = __shfl_xor(mx, 32, 64);
  float so = __shfl_xor(ssum, 32, 64);
  float ax = __shfl_xor(acc.x, 32, 64);
  float ay = __shfl_xor(acc.y, 32, 64);
  float az = __shfl_xor(acc.z, 32, 64);
  float aw = __shfl_xor(acc.w, 32, 64);
  float n  = fmaxf(mx, mo);
  float e0 = __expf(mx - n), e1 = __expf(mo - n);
  ssum  = ssum*e0 + so*e1;
  acc.x = acc.x*e0 + ax*e1;
  acc.y = acc.y*e0 + ay*e1;
  acc.z = acc.z*e0 + az*e1;
  acc.w = acc.w*e0 + aw*e1;

  if (half == 0){
    float inv = 1.0f / fmaxf(ssum, 1e-30f);
    float4 bv = *(const float4*)(pr + 33152 + c);
    float4 v = make_float4(acc.x*inv + bv.x, acc.y*inv + bv.y,
                           acc.z*inv + bv.z, acc.w*inv + bv.w);
    if (!last){
      v.x = fmaxf(v.x, 0.f); v.y = fmaxf(v.y, 0.f);
      v.z = fmaxf(v.z, 0.f); v.w = fmaxf(v.w, 0.f);
      *(float4*)(hnew + (size_t)node*D + c) = v;
    } else {
      *(float4*)(hnew + (size_t)node*D + c) = v;
      int isbf = flags[1];
      long long o = (long long)NG*D + (long long)node*D + c;
      stf(out, o+0, v.x, isbf); stf(out, o+1, v.y, isbf);
      stf(out, o+2, v.z, isbf); stf(out, o+3, v.w, isbf);
    }
  }
}

// ---------- two-stage mean pool ----------
__global__ __launch_bounds__(256) void k_pool1(const float* __restrict__ h, const u32* __restrict__ bnd,
                                               float* __restrict__ pool){
  int g = blockIdx.x >> 6, sl = blockIdx.x & 63;
  int ch = threadIdx.x & 127, ro = threadIdx.x >> 7;
  u32 b0 = bnd[g], b1 = bnd[g + 1];
  float acc = 0.f;
  for (u32 r = b0 + sl*2 + ro; r < b1; r += 128) acc += h[(size_t)r*D + ch];
  unsafeAtomicAdd(&pool[g*D + ch], acc);
}

__global__ void k_pool2(const float* __restrict__ pool, const u32* __restrict__ bnd,
                        void* __restrict__ out, const int* __restrict__ flags){
  int i = blockIdx.x*256 + threadIdx.x;
  if (i >= NG*D) return;
  int g = i >> 7;
  float c = (float)(bnd[g + 1] - bnd[g]);
  stf(out, i, pool[i] / fmaxf(c, 1.f), flags[1]);
}

extern "C" void kernel_launch(void* const* d_in, const int* in_sizes, int n_in,
                              void* d_out, int out_size, void* d_ws, size_t ws_size,
                              hipStream_t stream) {
  const void* x     = d_in[0];
  const void* ei    = d_in[1];
  const void* batch = d_in[2];

  const long long nf = (long long)NN*D*3 + 3*PL + NG*D;
  const long long nu = (NN + 1) + NN + ET + (NG + 1) + 2;
  if (ws_size < (size_t)(nf + nu)*4 + 256) return;

  float* ws    = (float*)d_ws;
  float* xf    = ws;                               // NN*D (h buffer each layer)
  float* xl    = xf + (size_t)NN*D;
  float* xr    = xl + (size_t)NN*D;
  float* prm   = xr + (size_t)NN*D;                // 3*PL
  float* pool  = prm + 3*PL;                       // NG*D
  u32*  offs   = (u32*)(pool + NG*D);              // NN+1
  u32*  cursor = offs + (NN + 1);                  // NN
  u32*  csr    = cursor + NN;                      // ET
  u32*  bnd    = csr + ET;                         // NG+1
  int*  flags  = (int*)(bnd + (NG + 1));           // 2

  k_detect<<<1, 256, 0, stream>>>(ei, x, flags);
  k_cvt<<<(NN*D)/256, 256, 0, stream>>>(x, xf, NN*D, flags);
  for (int l = 0; l < 3; ++l)
    k_cvtp<<<(PL + 255)/256, 256, 0, stream>>>(d_in[3+6*l+0], d_in[3+6*l+1], d_in[3+6*l+2],
                                               d_in[3+6*l+3], d_in[3+6*l+4], d_in[3+6*l+5],
                                               prm + (size_t)l*PL, flags);

  k_zero_u32<<<NN/256, 256, 0, stream>>>(cursor, NN);
  k_hist<<<ET/256, 256, 0, stream>>>(ei, cursor, flags);
  k_scan<<<1, 1024, 0, stream>>>(cursor, offs);
  k_scatter<<<ET/256, 256, 0, stream>>>(ei, cursor, csr, flags);
  k_bounds<<<1, 32, 0, stream>>>(batch, bnd, flags);
  k_zero_out32<<<8, 256, 0, stream>>>(pool, NG*D);

  for (int l = 0; l < 3; ++l){
    const float* p = prm + (size_t)l*PL;
    k_gemm<<<dim3(NN/64, 4), 256, 0, stream>>>(xf, p, xl, xr);
    k_node<<<NN/4, 256, 0, stream>>>(xl, xr, offs, csr, p, xf, d_out, flags, l == 2);
  }
  k_pool1<<<NG*64, 256, 0, stream>>>(xf, bnd, pool);
  k_pool2<<<8, 256, 0, stream>>>(pool, bnd, d_out, flags);
}

// Round 9
// 441.660 us; speedup vs baseline: 2.0862x; 1.1823x over previous
//
#include <hip/hip_runtime.h>

#define NN 40960
#define NE 655360
#define ET (NE + NN)        // 696320 edges incl self-loops
#define D 128
#define NG 16
#define PL 33280            // params per layer: WF[32768], bf[256], att[128], b[128]

typedef unsigned int u32;
typedef unsigned short u16;
typedef long long i64;

__device__ __forceinline__ float bf2f(u16 v){ return __uint_as_float(((u32)v)<<16); }
__device__ __forceinline__ u16 f2bf(float f){
  u32 u = __float_as_uint(f);
  return (u16)((u + 0x7FFFu + ((u>>16)&1u)) >> 16);
}
__device__ __forceinline__ int geti(const void* p, long long i, int f64, int bound){
  long long v = f64 ? ((const i64*)p)[i] : (long long)((const int*)p)[i];
  int x = (int)v;
  return (x < 0) ? 0 : ((x >= bound) ? bound-1 : x);
}
__device__ __forceinline__ void stf(void* p, long long i, float v, int isbf){
  if (isbf) ((u16*)p)[i] = f2bf(v); else ((float*)p)[i] = v;
}
__device__ __forceinline__ float rdf(const void* p, int i, int isbf){
  return isbf ? bf2f(((const u16*)p)[i]) : ((const float*)p)[i];
}

__global__ void k_zero_out32(float* __restrict__ o, int n){
  int i = blockIdx.x*256 + threadIdx.x;
  if (i < n) o[i] = 0.f;
}
__global__ void k_zero_u32(u32* __restrict__ o, int n){
  int i = blockIdx.x*256 + threadIdx.x;
  if (i < n) o[i] = 0u;
}

// flags[0]: indices are int64 ; flags[1]: floats are bf16
__global__ void k_detect(const void* __restrict__ ei, const void* __restrict__ x, int* __restrict__ flags){
  __shared__ int nz, cnt;
  if (threadIdx.x == 0){ nz = 0; cnt = 0; }
  __syncthreads();
  if (((const int*)ei)[2*threadIdx.x + 1] != 0) atomicAdd(&nz, 1);
  if (threadIdx.x < 128){
    u16 v = ((const u16*)x)[2*threadIdx.x];
    int ex = (v >> 7) & 0xFF;
    if (ex >= 100 && ex <= 140) atomicAdd(&cnt, 1);
  }
  __syncthreads();
  if (threadIdx.x == 0){
    flags[0] = (nz == 0) ? 1 : 0;
    flags[1] = (cnt >= 64) ? 1 : 0;
  }
}

__global__ void k_cvt(const void* __restrict__ src, float* __restrict__ dst, int n, const int* __restrict__ flags){
  int i = blockIdx.x*256 + threadIdx.x;
  if (i >= n) return;
  dst[i] = rdf(src, i, flags[1]);
}

// fused param pack: WF[k*256+gc] = (gc<128 ? Wl[k][gc] : Wr[k][gc-128]); bf[256]=bl|br; att; b
__global__ void k_cvtp(const void* Wl, const void* bl, const void* Wr, const void* br,
                       const void* att, const void* b, float* __restrict__ p, const int* __restrict__ flags){
  int i = blockIdx.x*256 + threadIdx.x;
  if (i >= PL) return;
  int isbf = flags[1];
  float v;
  if (i < 32768){
    int k = i >> 8, gc = i & 255;
    v = (gc < 128) ? rdf(Wl, k*128 + gc, isbf) : rdf(Wr, k*128 + gc - 128, isbf);
  }
  else if (i < 33024){ int gc = i - 32768; v = (gc < 128) ? rdf(bl, gc, isbf) : rdf(br, gc - 128, isbf); }
  else if (i < 33152) v = rdf(att, i - 33024, isbf);
  else                v = rdf(b, i - 33152, isbf);
  p[i] = v;
}

// ---------- CSR build (by dst, self-loops appended); entry packs src|dst<<16 ----------
__global__ void k_hist(const void* __restrict__ ei, u32* __restrict__ cursor, const int* __restrict__ flags){
  int e = blockIdx.x*256 + threadIdx.x;
  if (e >= ET) return;
  int dd = (e < NE) ? geti(ei, (long long)NE + e, flags[0], NN) : e - NE;
  atomicAdd(&cursor[dd], 1u);
}

__global__ __launch_bounds__(1024) void k_scan(u32* __restrict__ cursor, u32* __restrict__ offs){
  __shared__ u32 part[1024];
  int t = threadIdx.x;
  int base = t * 40;
  u32 s = 0;
  #pragma unroll 4
  for (int i = 0; i < 40; ++i) s += cursor[base + i];
  part[t] = s;
  __syncthreads();
  for (int off = 1; off < 1024; off <<= 1){
    u32 v = (t >= off) ? part[t - off] : 0u;
    __syncthreads();
    part[t] += v;
    __syncthreads();
  }
  u32 run = (t == 0) ? 0u : part[t - 1];
  for (int i = 0; i < 40; ++i){
    u32 d = cursor[base + i];
    offs[base + i] = run;
    cursor[base + i] = run;
    run += d;
  }
  if (t == 1023) offs[NN] = run;
}

__global__ void k_scatter(const void* __restrict__ ei, u32* __restrict__ cursor,
                          u32* __restrict__ csr, const int* __restrict__ flags){
  int e = blockIdx.x*256 + threadIdx.x;
  if (e >= ET) return;
  int f = flags[0];
  int s, dd;
  if (e < NE){ s = geti(ei, e, f, NN); dd = geti(ei, (long long)NE + e, f, NN); }
  else { s = dd = e - NE; }
  u32 pos = atomicAdd(&cursor[dd], 1u);
  csr[pos] = (u32)s | ((u32)dd << 16);
}

__global__ void k_bounds(const void* __restrict__ batch, u32* __restrict__ bnd, const int* __restrict__ flags){
  int g = threadIdx.x;
  if (g > NG) return;
  if (g == NG){ bnd[NG] = NN; return; }
  int f = flags[0];
  int lo = 0, hi = NN;
  while (lo < hi){
    int mid = (lo + hi) >> 1;
    if (geti(batch, mid, f, NG) < g) lo = mid + 1; else hi = mid;
  }
  bnd[g] = (u32)lo;
}

// ---------- GEMM: 64 rows x 64 cols per block, K=128 one-shot, 4x4 register tile ----------
// Xs row dimension is XOR-swizzled at float4-block granularity to kill the 32-way
// bank conflict on staging writes (bank was row%32, constant across a wave).
__global__ __launch_bounds__(256) void k_gemm(const float* __restrict__ X, const float* __restrict__ pr,
                                              float* __restrict__ xl, float* __restrict__ xr)
{
  __shared__ float Xs[128][64];
  __shared__ float Ws[128][64];
  int tid = threadIdx.x;
  int row0 = blockIdx.x * 64;
  int bc0  = blockIdx.y * 64;

  const float4* Xg = (const float4*)(X + (size_t)row0 * D);
  #pragma unroll
  for (int i = 0; i < 8; ++i){
    int idx = tid + i*256;
    int row = idx >> 5, k4 = idx & 31;
    float4 v = Xg[(size_t)row*32 + k4];
    int rs = row ^ ((k4 & 15) << 2);        // swizzle: block = row_blk ^ (k>>2 & 15)
    Xs[k4*4+0][rs] = v.x;
    Xs[k4*4+1][rs] = v.y;
    Xs[k4*4+2][rs] = v.z;
    Xs[k4*4+3][rs] = v.w;
  }
  #pragma unroll
  for (int i = 0; i < 8; ++i){
    int idx = tid + i*256;
    int k = idx >> 4, c4 = idx & 15;
    float4 v = *(const float4*)(pr + (size_t)k*256 + bc0 + c4*4);
    *(float4*)&Ws[k][c4*4] = v;
  }
  __syncthreads();

  int ty = tid >> 4, tx = tid & 15;
  int r = ty*4, c = tx*4;
  float4 bias = *(const float4*)(pr + 32768 + bc0 + c);
  float acc[4][4];
  #pragma unroll
  for (int i = 0; i < 4; ++i){
    acc[i][0] = bias.x; acc[i][1] = bias.y; acc[i][2] = bias.z; acc[i][3] = bias.w;
  }
  #pragma unroll 4
  for (int k = 0; k < 128; ++k){
    int swb = ((k >> 2) & 15) << 2;
    float4 a = *(const float4*)&Xs[k][r ^ swb];
    float4 b = *(const float4*)&Ws[k][c];
    acc[0][0] = fmaf(a.x, b.x, acc[0][0]); acc[0][1] = fmaf(a.x, b.y, acc[0][1]);
    acc[0][2] = fmaf(a.x, b.z, acc[0][2]); acc[0][3] = fmaf(a.x, b.w, acc[0][3]);
    acc[1][0] = fmaf(a.y, b.x, acc[1][0]); acc[1][1] = fmaf(a.y, b.y, acc[1][1]);
    acc[1][2] = fmaf(a.y, b.z, acc[1][2]); acc[1][3] = fmaf(a.y, b.w, acc[1][3]);
    acc[2][0] = fmaf(a.z, b.x, acc[2][0]); acc[2][1] = fmaf(a.z, b.y, acc[2][1]);
    acc[2][2] = fmaf(a.z, b.z, acc[2][2]); acc[2][3] = fmaf(a.z, b.w, acc[2][3]);
    acc[3][0] = fmaf(a.w, b.x, acc[3][0]); acc[3][1] = fmaf(a.w, b.y, acc[3][1]);
    acc[3][2] = fmaf(a.w, b.z, acc[3][2]); acc[3][3] = fmaf(a.w, b.w, acc[3][3]);
  }
  float* base = (bc0 < 128) ? xl : xr;
  int co = (bc0 < 128) ? bc0 + c : bc0 - 128 + c;
  #pragma unroll
  for (int i = 0; i < 4; ++i)
    *(float4*)(base + (size_t)(row0 + r + i)*D + co) =
        make_float4(acc[i][0], acc[i][1], acc[i][2], acc[i][3]);
}

// ---------- fused per-node attention: wave per node, 2 edges/iter, 4 ch/lane ----------
__global__ __launch_bounds__(256) void k_node(const float* __restrict__ xl, const float* __restrict__ xr,
    const u32* __restrict__ offs, const u32* __restrict__ csr, const float* __restrict__ pr,
    float* __restrict__ hnew, void* __restrict__ out, const int* __restrict__ flags, int last)
{
  int node = blockIdx.x*4 + (threadIdx.x >> 6);
  int lane = threadIdx.x & 63;
  int half = lane >> 5;
  int c = (lane & 31) * 4;
  float4 xrv  = *(const float4*)(xr + (size_t)node*D + c);
  float4 attv = *(const float4*)(pr + 33024 + c);
  u32 j0 = offs[node], j1 = offs[node + 1];

  float mx = -1e30f, ssum = 0.f;
  float4 acc = make_float4(0.f, 0.f, 0.f, 0.f);
  for (u32 j = j0 + half; j < j1; j += 2){
    int s = (int)(csr[j] & 0xFFFFu);
    float4 g = *(const float4*)(xl + (size_t)s*D + c);
    float m, p;
    m = g.x + xrv.x; m = (m > 0.f) ? m : 0.2f*m; p  = m * attv.x;
    m = g.y + xrv.y; m = (m > 0.f) ? m : 0.2f*m; p  = fmaf(m, attv.y, p);
    m = g.z + xrv.z; m = (m > 0.f) ? m : 0.2f*m; p  = fmaf(m, attv.z, p);
    m = g.w + xrv.w; m = (m > 0.f) ? m : 0.2f*m; p  = fmaf(m, attv.w, p);
    p += __shfl_xor(p, 1, 64);
    p += __shfl_xor(p, 2, 64);
    p += __shfl_xor(p, 4, 64);     // all 8 head-lanes now hold the logit
    float n  = fmaxf(mx, p);
    float eo = __expf(mx - n), en = __expf(p - n);
    ssum  = fmaf(ssum, eo, en);
    acc.x = fmaf(acc.x, eo, en * g.x);
    acc.y = fmaf(acc.y, eo, en * g.y);
    acc.z = fmaf(acc.z, eo, en * g.z);
    acc.w = fmaf(acc.w, eo, en * g.w);
    mx = n;
  }
  // merge the two half-wave online-softmax states (lanes l and l+32 share channels)
  float mo = __shfl_xor(mx, 32, 64);
  float so = __shfl_xor(ssum, 32, 64);
  float ax = __shfl_xor(acc.x, 32, 64);
  float ay = __shfl_xor(acc.y, 32, 64);
  float az = __shfl_xor(acc.z, 32, 64);
  float aw = __shfl_xor(acc.w, 32, 64);
  float n  = fmaxf(mx, mo);
  float e0 = __expf(mx - n), e1 = __expf(mo - n);
  ssum  = ssum*e0 + so*e1;
  acc.x = acc.x*e0 + ax*e1;
  acc.y = acc.y*e0 + ay*e1;
  acc.z = acc.z*e0 + az*e1;
  acc.w = acc.w*e0 + aw*e1;

  if (half == 0){
    float inv = 1.0f / fmaxf(ssum, 1e-30f);
    float4 bv = *(const float4*)(pr + 33152 + c);
    float4 v = make_float4(acc.x*inv + bv.x, acc.y*inv + bv.y,
                           acc.z*inv + bv.z, acc.w*inv + bv.w);
    if (!last){
      v.x = fmaxf(v.x, 0.f); v.y = fmaxf(v.y, 0.f);
      v.z = fmaxf(v.z, 0.f); v.w = fmaxf(v.w, 0.f);
      *(float4*)(hnew + (size_t)node*D + c) = v;
    } else {
      *(float4*)(hnew + (size_t)node*D + c) = v;
      int isbf = flags[1];
      long long o = (long long)NG*D + (long long)node*D + c;
      stf(out, o+0, v.x, isbf); stf(out, o+1, v.y, isbf);
      stf(out, o+2, v.z, isbf); stf(out, o+3, v.w, isbf);
    }
  }
}

// ---------- two-stage mean pool ----------
__global__ __launch_bounds__(256) void k_pool1(const float* __restrict__ h, const u32* __restrict__ bnd,
                                               float* __restrict__ pool){
  int g = blockIdx.x >> 6, sl = blockIdx.x & 63;
  int ch = threadIdx.x & 127, ro = threadIdx.x >> 7;
  u32 b0 = bnd[g], b1 = bnd[g + 1];
  float acc = 0.f;
  for (u32 r = b0 + sl*2 + ro; r < b1; r += 128) acc += h[(size_t)r*D + ch];
  unsafeAtomicAdd(&pool[g*D + ch], acc);
}

__global__ void k_pool2(const float* __restrict__ pool, const u32* __restrict__ bnd,
                        void* __restrict__ out, const int* __restrict__ flags){
  int i = blockIdx.x*256 + threadIdx.x;
  if (i >= NG*D) return;
  int g = i >> 7;
  float c = (float)(bnd[g + 1] - bnd[g]);
  stf(out, i, pool[i] / fmaxf(c, 1.f), flags[1]);
}

extern "C" void kernel_launch(void* const* d_in, const int* in_sizes, int n_in,
                              void* d_out, int out_size, void* d_ws, size_t ws_size,
                              hipStream_t stream) {
  const void* x     = d_in[0];
  const void* ei    = d_in[1];
  const void* batch = d_in[2];

  const long long nf = (long long)NN*D*3 + 3*PL + NG*D;
  const long long nu = (NN + 1) + NN + ET + (NG + 1) + 2;
  if (ws_size < (size_t)(nf + nu)*4 + 256) return;

  float* ws    = (float*)d_ws;
  float* xf    = ws;                               // NN*D (h buffer each layer)
  float* xl    = xf + (size_t)NN*D;
  float* xr    = xl + (size_t)NN*D;
  float* prm   = xr + (size_t)NN*D;                // 3*PL
  float* pool  = prm + 3*PL;                       // NG*D
  u32*  offs   = (u32*)(pool + NG*D);              // NN+1
  u32*  cursor = offs + (NN + 1);                  // NN
  u32*  csr    = cursor + NN;                      // ET
  u32*  bnd    = csr + ET;                         // NG+1
  int*  flags  = (int*)(bnd + (NG + 1));           // 2

  k_detect<<<1, 256, 0, stream>>>(ei, x, flags);
  k_cvt<<<(NN*D)/256, 256, 0, stream>>>(x, xf, NN*D, flags);
  for (int l = 0; l < 3; ++l)
    k_cvtp<<<(PL + 255)/256, 256, 0, stream>>>(d_in[3+6*l+0], d_in[3+6*l+1], d_in[3+6*l+2],
                                               d_in[3+6*l+3], d_in[3+6*l+4], d_in[3+6*l+5],
                                               prm + (size_t)l*PL, flags);

  k_zero_u32<<<NN/256, 256, 0, stream>>>(cursor, NN);
  k_hist<<<ET/256, 256, 0, stream>>>(ei, cursor, flags);
  k_scan<<<1, 1024, 0, stream>>>(cursor, offs);
  k_scatter<<<ET/256, 256, 0, stream>>>(ei, cursor, csr, flags);
  k_bounds<<<1, 32, 0, stream>>>(batch, bnd, flags);
  k_zero_out32<<<8, 256, 0, stream>>>(pool, NG*D);

  for (int l = 0; l < 3; ++l){
    const float* p = prm + (size_t)l*PL;
    k_gemm<<<dim3(NN/64, 4), 256, 0, stream>>>(xf, p, xl, xr);
    k_node<<<NN/4, 256, 0, stream>>>(xl, xr, offs, csr, p, xf, d_out, flags, l == 2);
  }
  k_pool1<<<NG*64, 256, 0, stream>>>(xf, bnd, pool);
  k_pool2<<<8, 256, 0, stream>>>(pool, bnd, d_out, flags);
}

// Round 10
// 434.276 us; speedup vs baseline: 2.1217x; 1.0170x over previous
//
#include <hip/hip_runtime.h>

#define NN 40960
#define NE 655360
#define ET (NE + NN)        // 696320 edges incl self-loops
#define D 128
#define NG 16
#define PL 33280            // params per layer: WF[32768], bf[256], att[128], b[128]

typedef unsigned int u32;
typedef unsigned short u16;
typedef long long i64;

__device__ __forceinline__ float bf2f(u16 v){ return __uint_as_float(((u32)v)<<16); }
__device__ __forceinline__ u16 f2bf(float f){
  u32 u = __float_as_uint(f);
  return (u16)((u + 0x7FFFu + ((u>>16)&1u)) >> 16);
}
__device__ __forceinline__ int geti(const void* p, long long i, int f64, int bound){
  long long v = f64 ? ((const i64*)p)[i] : (long long)((const int*)p)[i];
  int x = (int)v;
  return (x < 0) ? 0 : ((x >= bound) ? bound-1 : x);
}
__device__ __forceinline__ void stf(void* p, long long i, float v, int isbf){
  if (isbf) ((u16*)p)[i] = f2bf(v); else ((float*)p)[i] = v;
}
__device__ __forceinline__ float rdf(const void* p, int i, int isbf){
  return isbf ? bf2f(((const u16*)p)[i]) : ((const float*)p)[i];
}

__global__ void k_zero_out32(float* __restrict__ o, int n){
  int i = blockIdx.x*256 + threadIdx.x;
  if (i < n) o[i] = 0.f;
}

// block 0: dtype detect; blocks 1..160: zero cursor; blocks 161..168: zero pool
__global__ void k_setup(const void* __restrict__ ei, const void* __restrict__ x,
                        int* __restrict__ flags, u32* __restrict__ cursor, float* __restrict__ pool){
  int b = blockIdx.x;
  if (b == 0){
    __shared__ int nz, cnt;
    if (threadIdx.x == 0){ nz = 0; cnt = 0; }
    __syncthreads();
    if (((const int*)ei)[2*threadIdx.x + 1] != 0) atomicAdd(&nz, 1);
    if (threadIdx.x < 128){
      u16 v = ((const u16*)x)[2*threadIdx.x];
      int ex = (v >> 7) & 0xFF;
      if (ex >= 100 && ex <= 140) atomicAdd(&cnt, 1);
    }
    __syncthreads();
    if (threadIdx.x == 0){
      flags[0] = (nz == 0) ? 1 : 0;
      flags[1] = (cnt >= 64) ? 1 : 0;
    }
  } else if (b <= 160){
    cursor[(b-1)*256 + threadIdx.x] = 0u;
  } else {
    int i = (b-161)*256 + threadIdx.x;
    if (i < NG*D) pool[i] = 0.f;
  }
}

__global__ void k_cvt(const void* __restrict__ src, float* __restrict__ dst, int n, const int* __restrict__ flags){
  int i = blockIdx.x*256 + threadIdx.x;
  if (i >= n) return;
  dst[i] = rdf(src, i, flags[1]);
}

// fused param pack: WF[k*256+gc] = (gc<128 ? Wl[k][gc] : Wr[k][gc-128]); bf[256]=bl|br; att; b
__global__ void k_cvtp(const void* Wl, const void* bl, const void* Wr, const void* br,
                       const void* att, const void* b, float* __restrict__ p, const int* __restrict__ flags){
  int i = blockIdx.x*256 + threadIdx.x;
  if (i >= PL) return;
  int isbf = flags[1];
  float v;
  if (i < 32768){
    int k = i >> 8, gc = i & 255;
    v = (gc < 128) ? rdf(Wl, k*128 + gc, isbf) : rdf(Wr, k*128 + gc - 128, isbf);
  }
  else if (i < 33024){ int gc = i - 32768; v = (gc < 128) ? rdf(bl, gc, isbf) : rdf(br, gc - 128, isbf); }
  else if (i < 33152) v = rdf(att, i - 33024, isbf);
  else                v = rdf(b, i - 33152, isbf);
  p[i] = v;
}

// ---------- CSR build (by dst, self-loops appended); entry packs src|dst<<16 ----------
__global__ void k_hist(const void* __restrict__ ei, u32* __restrict__ cursor, const int* __restrict__ flags){
  int e = blockIdx.x*256 + threadIdx.x;
  if (e >= ET) return;
  int dd = (e < NE) ? geti(ei, (long long)NE + e, flags[0], NN) : e - NE;
  atomicAdd(&cursor[dd], 1u);
}

__global__ __launch_bounds__(1024) void k_scan(u32* __restrict__ cursor, u32* __restrict__ offs){
  __shared__ u32 part[1024];
  int t = threadIdx.x;
  int base = t * 40;
  u32 s = 0;
  #pragma unroll 4
  for (int i = 0; i < 40; ++i) s += cursor[base + i];
  part[t] = s;
  __syncthreads();
  for (int off = 1; off < 1024; off <<= 1){
    u32 v = (t >= off) ? part[t - off] : 0u;
    __syncthreads();
    part[t] += v;
    __syncthreads();
  }
  u32 run = (t == 0) ? 0u : part[t - 1];
  for (int i = 0; i < 40; ++i){
    u32 d = cursor[base + i];
    offs[base + i] = run;
    cursor[base + i] = run;
    run += d;
  }
  if (t == 1023) offs[NN] = run;
}

__global__ void k_scatter(const void* __restrict__ ei, u32* __restrict__ cursor,
                          u32* __restrict__ csr, const int* __restrict__ flags){
  int e = blockIdx.x*256 + threadIdx.x;
  if (e >= ET) return;
  int f = flags[0];
  int s, dd;
  if (e < NE){ s = geti(ei, e, f, NN); dd = geti(ei, (long long)NE + e, f, NN); }
  else { s = dd = e - NE; }
  u32 pos = atomicAdd(&cursor[dd], 1u);
  csr[pos] = (u32)s | ((u32)dd << 16);
}

__global__ void k_bounds(const void* __restrict__ batch, u32* __restrict__ bnd, const int* __restrict__ flags){
  int g = threadIdx.x;
  if (g > NG) return;
  if (g == NG){ bnd[NG] = NN; return; }
  int f = flags[0];
  int lo = 0, hi = NN;
  while (lo < hi){
    int mid = (lo + hi) >> 1;
    if (geti(batch, mid, f, NG) < g) lo = mid + 1; else hi = mid;
  }
  bnd[g] = (u32)lo;
}

// ---------- GEMM: 64x64 tile, BK=64 two-step (34 KB LDS -> 4 blocks/CU), 4x4 reg tile ----------
// Xs row dim XOR-swizzled (kills 32-way staging conflict); Ws padded to stride 68
// (stage-writes bank-uniform, reads 2-way free).
__global__ __launch_bounds__(256, 4) void k_gemm(const float* __restrict__ X, const float* __restrict__ pr,
                                                 float* __restrict__ xl, float* __restrict__ xr)
{
  __shared__ float Xs[64][64];
  __shared__ float Ws[64][68];
  int tid = threadIdx.x;
  int row0 = blockIdx.x * 64;
  int bc0  = blockIdx.y * 64;

  int ty = tid >> 4, tx = tid & 15;
  int r = ty*4, c = tx*4;
  float4 bias = *(const float4*)(pr + 32768 + bc0 + c);
  float acc[4][4];
  #pragma unroll
  for (int i = 0; i < 4; ++i){
    acc[i][0] = bias.x; acc[i][1] = bias.y; acc[i][2] = bias.z; acc[i][3] = bias.w;
  }

  #pragma unroll
  for (int kt = 0; kt < 2; ++kt){
    // stage X tile: rows 64 x k 64
    const float* Xb = X + (size_t)row0*D + kt*64;
    #pragma unroll
    for (int i = 0; i < 4; ++i){
      int idx = tid + i*256;
      int row = idx >> 4, k4 = idx & 15;
      float4 v = *(const float4*)(Xb + (size_t)row*D + k4*4);
      int rs = row ^ (k4 << 2);
      Xs[k4*4+0][rs] = v.x;
      Xs[k4*4+1][rs] = v.y;
      Xs[k4*4+2][rs] = v.z;
      Xs[k4*4+3][rs] = v.w;
    }
    // stage W tile
    const float* Wb = pr + (size_t)kt*64*256 + bc0;
    #pragma unroll
    for (int i = 0; i < 4; ++i){
      int idx = tid + i*256;
      int k = idx >> 4, c4 = idx & 15;
      float4 v = *(const float4*)(Wb + (size_t)k*256 + c4*4);
      *(float4*)&Ws[k][c4*4] = v;
    }
    __syncthreads();
    #pragma unroll 4
    for (int k = 0; k < 64; ++k){
      int swb = (k >> 2) << 2;
      float4 a = *(const float4*)&Xs[k][r ^ swb];
      float4 b = *(const float4*)&Ws[k][c];
      acc[0][0] = fmaf(a.x, b.x, acc[0][0]); acc[0][1] = fmaf(a.x, b.y, acc[0][1]);
      acc[0][2] = fmaf(a.x, b.z, acc[0][2]); acc[0][3] = fmaf(a.x, b.w, acc[0][3]);
      acc[1][0] = fmaf(a.y, b.x, acc[1][0]); acc[1][1] = fmaf(a.y, b.y, acc[1][1]);
      acc[1][2] = fmaf(a.y, b.z, acc[1][2]); acc[1][3] = fmaf(a.y, b.w, acc[1][3]);
      acc[2][0] = fmaf(a.z, b.x, acc[2][0]); acc[2][1] = fmaf(a.z, b.y, acc[2][1]);
      acc[2][2] = fmaf(a.z, b.z, acc[2][2]); acc[2][3] = fmaf(a.z, b.w, acc[2][3]);
      acc[3][0] = fmaf(a.w, b.x, acc[3][0]); acc[3][1] = fmaf(a.w, b.y, acc[3][1]);
      acc[3][2] = fmaf(a.w, b.z, acc[3][2]); acc[3][3] = fmaf(a.w, b.w, acc[3][3]);
    }
    __syncthreads();
  }

  float* base = (bc0 < 128) ? xl : xr;
  int co = (bc0 < 128) ? bc0 + c : bc0 - 128 + c;
  #pragma unroll
  for (int i = 0; i < 4; ++i)
    *(float4*)(base + (size_t)(row0 + r + i)*D + co) =
        make_float4(acc[i][0], acc[i][1], acc[i][2], acc[i][3]);
}

// ---------- fused per-node attention: wave per node, 2 edges/iter, defer-max softmax ----------
__global__ __launch_bounds__(256) void k_node(const float* __restrict__ xl, const float* __restrict__ xr,
    const u32* __restrict__ offs, const u32* __restrict__ csr, const float* __restrict__ pr,
    float* __restrict__ hnew, void* __restrict__ out, const int* __restrict__ flags, int last)
{
  int node = blockIdx.x*4 + (threadIdx.x >> 6);
  int lane = threadIdx.x & 63;
  int half = lane >> 5;
  int c = (lane & 31) * 4;
  float4 xrv  = *(const float4*)(xr + (size_t)node*D + c);
  float4 attv = *(const float4*)(pr + 33024 + c);
  u32 j0 = offs[node], j1 = offs[node + 1];

  float mx = -1e30f, ssum = 0.f;
  float4 acc = make_float4(0.f, 0.f, 0.f, 0.f);
  for (u32 j = j0 + half; j < j1; j += 2){
    int s = (int)(csr[j] & 0xFFFFu);
    float4 g = *(const float4*)(xl + (size_t)s*D + c);
    float m, p;
    m = g.x + xrv.x; p = fmaxf(m, 0.2f*m) * attv.x;
    m = g.y + xrv.y; p = fmaf(fmaxf(m, 0.2f*m), attv.y, p);
    m = g.z + xrv.z; p = fmaf(fmaxf(m, 0.2f*m), attv.z, p);
    m = g.w + xrv.w; p = fmaf(fmaxf(m, 0.2f*m), attv.w, p);
    p += __shfl_xor(p, 1, 64);
    p += __shfl_xor(p, 2, 64);
    p += __shfl_xor(p, 4, 64);     // all 8 head-lanes hold the logit
    if (p > mx + 8.f){             // rare: deferred-max rescale (always taken on 1st edge)
      float eo = __expf(mx - p);   // exp(-1e30-...)=0 on first edge
      ssum  *= eo;
      acc.x *= eo; acc.y *= eo; acc.z *= eo; acc.w *= eo;
      mx = p;
    }
    float en = __expf(p - mx);     // <= e^8, harmless in f32
    ssum += en;
    acc.x = fmaf(en, g.x, acc.x);
    acc.y = fmaf(en, g.y, acc.y);
    acc.z = fmaf(en, g.z, acc.z);
    acc.w = fmaf(en, g.w, acc.w);
  }
  // merge the two half-wave states (lanes l and l+32 share channels)
  float mo = __shfl_xor(mx, 32, 64);
  float so = __shfl_xor(ssum, 32, 64);
  float ax = __shfl_xor(acc.x, 32, 64);
  float ay = __shfl_xor(acc.y, 32, 64);
  float az = __shfl_xor(acc.z, 32, 64);
  float aw = __shfl_xor(acc.w, 32, 64);
  float n  = fmaxf(mx, mo);
  float e0 = __expf(mx - n), e1 = __expf(mo - n);
  ssum  = ssum*e0 + so*e1;
  acc.x = acc.x*e0 + ax*e1;
  acc.y = acc.y*e0 + ay*e1;
  acc.z = acc.z*e0 + az*e1;
  acc.w = acc.w*e0 + aw*e1;

  if (half == 0){
    float inv = 1.0f / fmaxf(ssum, 1e-30f);
    float4 bv = *(const float4*)(pr + 33152 + c);
    float4 v = make_float4(acc.x*inv + bv.x, acc.y*inv + bv.y,
                           acc.z*inv + bv.z, acc.w*inv + bv.w);
    if (!last){
      v.x = fmaxf(v.x, 0.f); v.y = fmaxf(v.y, 0.f);
      v.z = fmaxf(v.z, 0.f); v.w = fmaxf(v.w, 0.f);
      *(float4*)(hnew + (size_t)node*D + c) = v;
    } else {
      *(float4*)(hnew + (size_t)node*D + c) = v;
      int isbf = flags[1];
      long long o = (long long)NG*D + (long long)node*D + c;
      stf(out, o+0, v.x, isbf); stf(out, o+1, v.y, isbf);
      stf(out, o+2, v.z, isbf); stf(out, o+3, v.w, isbf);
    }
  }
}

// ---------- two-stage mean pool ----------
__global__ __launch_bounds__(256) void k_pool1(const float* __restrict__ h, const u32* __restrict__ bnd,
                                               float* __restrict__ pool){
  int g = blockIdx.x >> 6, sl = blockIdx.x & 63;
  int ch = threadIdx.x & 127, ro = threadIdx.x >> 7;
  u32 b0 = bnd[g], b1 = bnd[g + 1];
  float acc = 0.f;
  for (u32 r = b0 + sl*2 + ro; r < b1; r += 128) acc += h[(size_t)r*D + ch];
  unsafeAtomicAdd(&pool[g*D + ch], acc);
}

__global__ void k_pool2(const float* __restrict__ pool, const u32* __restrict__ bnd,
                        void* __restrict__ out, const int* __restrict__ flags){
  int i = blockIdx.x*256 + threadIdx.x;
  if (i >= NG*D) return;
  int g = i >> 7;
  float c = (float)(bnd[g + 1] - bnd[g]);
  stf(out, i, pool[i] / fmaxf(c, 1.f), flags[1]);
}

extern "C" void kernel_launch(void* const* d_in, const int* in_sizes, int n_in,
                              void* d_out, int out_size, void* d_ws, size_t ws_size,
                              hipStream_t stream) {
  const void* x     = d_in[0];
  const void* ei    = d_in[1];
  const void* batch = d_in[2];

  const long long nf = (long long)NN*D*3 + 3*PL + NG*D;
  const long long nu = (NN + 1) + NN + ET + (NG + 1) + 2;
  if (ws_size < (size_t)(nf + nu)*4 + 256) return;

  float* ws    = (float*)d_ws;
  float* xf    = ws;                               // NN*D (h buffer each layer)
  float* xl    = xf + (size_t)NN*D;
  float* xr    = xl + (size_t)NN*D;
  float* prm   = xr + (size_t)NN*D;                // 3*PL
  float* pool  = prm + 3*PL;                       // NG*D
  u32*  offs   = (u32*)(pool + NG*D);              // NN+1
  u32*  cursor = offs + (NN + 1);                  // NN
  u32*  csr    = cursor + NN;                      // ET
  u32*  bnd    = csr + ET;                         // NG+1
  int*  flags  = (int*)(bnd + (NG + 1));           // 2

  k_setup<<<169, 256, 0, stream>>>(ei, x, flags, cursor, pool);
  k_cvt<<<(NN*D)/256, 256, 0, stream>>>(x, xf, NN*D, flags);
  for (int l = 0; l < 3; ++l)
    k_cvtp<<<(PL + 255)/256, 256, 0, stream>>>(d_in[3+6*l+0], d_in[3+6*l+1], d_in[3+6*l+2],
                                               d_in[3+6*l+3], d_in[3+6*l+4], d_in[3+6*l+5],
                                               prm + (size_t)l*PL, flags);

  k_hist<<<ET/256, 256, 0, stream>>>(ei, cursor, flags);
  k_scan<<<1, 1024, 0, stream>>>(cursor, offs);
  k_scatter<<<ET/256, 256, 0, stream>>>(ei, cursor, csr, flags);
  k_bounds<<<1, 32, 0, stream>>>(batch, bnd, flags);

  for (int l = 0; l < 3; ++l){
    const float* p = prm + (size_t)l*PL;
    k_gemm<<<dim3(NN/64, 4), 256, 0, stream>>>(xf, p, xl, xr);
    k_node<<<NN/4, 256, 0, stream>>>(xl, xr, offs, csr, p, xf, d_out, flags, l == 2);
  }
  k_pool1<<<NG*64, 256, 0, stream>>>(xf, bnd, pool);
  k_pool2<<<8, 256, 0, stream>>>(pool, bnd, d_out, flags);
}

// Round 11
// 394.489 us; speedup vs baseline: 2.3357x; 1.1009x over previous
//
#include <hip/hip_runtime.h>

#define NN 40960
#define NE 655360
#define ET (NE + NN)        // 696320 edges incl self-loops
#define D 128
#define NG 16
#define PL 33280            // params per layer: WF[32768], bf[256], att[128], b[128]

typedef unsigned int u32;
typedef unsigned short u16;
typedef long long i64;

struct P18 { const void* p[18]; };

__device__ __forceinline__ float bf2f(u16 v){ return __uint_as_float(((u32)v)<<16); }
__device__ __forceinline__ u16 f2bf(float f){
  u32 u = __float_as_uint(f);
  return (u16)((u + 0x7FFFu + ((u>>16)&1u)) >> 16);
}
__device__ __forceinline__ int geti(const void* p, long long i, int f64, int bound){
  long long v = f64 ? ((const i64*)p)[i] : (long long)((const int*)p)[i];
  int x = (int)v;
  return (x < 0) ? 0 : ((x >= bound) ? bound-1 : x);
}
__device__ __forceinline__ void stf(void* p, long long i, float v, int isbf){
  if (isbf) ((u16*)p)[i] = f2bf(v); else ((float*)p)[i] = v;
}
__device__ __forceinline__ float rdf(const void* p, int i, int isbf){
  return isbf ? bf2f(((const u16*)p)[i]) : ((const float*)p)[i];
}

// block 0: dtype detect; blocks 1..160: zero cursor; blocks 161..168: zero pool
__global__ void k_setup(const void* __restrict__ ei, const void* __restrict__ x,
                        int* __restrict__ flags, u32* __restrict__ cursor, float* __restrict__ pool){
  int b = blockIdx.x;
  if (b == 0){
    __shared__ int nz, cnt;
    if (threadIdx.x == 0){ nz = 0; cnt = 0; }
    __syncthreads();
    if (((const int*)ei)[2*threadIdx.x + 1] != 0) atomicAdd(&nz, 1);
    if (threadIdx.x < 128){
      u16 v = ((const u16*)x)[2*threadIdx.x];
      int ex = (v >> 7) & 0xFF;
      if (ex >= 100 && ex <= 140) atomicAdd(&cnt, 1);
    }
    __syncthreads();
    if (threadIdx.x == 0){
      flags[0] = (nz == 0) ? 1 : 0;
      flags[1] = (cnt >= 64) ? 1 : 0;
    }
  } else if (b <= 160){
    cursor[(b-1)*256 + threadIdx.x] = 0u;
  } else {
    int i = (b-161)*256 + threadIdx.x;
    if (i < NG*D) pool[i] = 0.f;
  }
}

__global__ void k_cvt(const void* __restrict__ src, float* __restrict__ dst, int n, const int* __restrict__ flags){
  int i = blockIdx.x*256 + threadIdx.x;
  if (i >= n) return;
  dst[i] = rdf(src, i, flags[1]);
}

// all-layer param pack (one launch): blockIdx.y = layer
__global__ void k_cvtp(P18 ps, float* __restrict__ prm, const int* __restrict__ flags){
  int l = blockIdx.y;
  int i = blockIdx.x*256 + threadIdx.x;
  if (i >= PL) return;
  const void* Wl  = ps.p[6*l+0];
  const void* bl  = ps.p[6*l+1];
  const void* Wr  = ps.p[6*l+2];
  const void* br  = ps.p[6*l+3];
  const void* att = ps.p[6*l+4];
  const void* b   = ps.p[6*l+5];
  int isbf = flags[1];
  float v;
  if (i < 32768){
    int k = i >> 8, gc = i & 255;
    v = (gc < 128) ? rdf(Wl, k*128 + gc, isbf) : rdf(Wr, k*128 + gc - 128, isbf);
  }
  else if (i < 33024){ int gc = i - 32768; v = (gc < 128) ? rdf(bl, gc, isbf) : rdf(br, gc - 128, isbf); }
  else if (i < 33152) v = rdf(att, i - 33024, isbf);
  else                v = rdf(b, i - 33152, isbf);
  prm[(size_t)l*PL + i] = v;
}

// ---------- CSR build (by dst, self-loops appended); entry packs src|dst<<16 ----------
__global__ void k_hist(const void* __restrict__ ei, u32* __restrict__ cursor, const int* __restrict__ flags){
  int e = blockIdx.x*256 + threadIdx.x;
  if (e >= ET) return;
  int dd = (e < NE) ? geti(ei, (long long)NE + e, flags[0], NN) : e - NE;
  atomicAdd(&cursor[dd], 1u);
}

__global__ __launch_bounds__(1024) void k_scan(u32* __restrict__ cursor, u32* __restrict__ offs){
  __shared__ u32 part[1024];
  int t = threadIdx.x;
  int base = t * 40;
  u32 s = 0;
  #pragma unroll 4
  for (int i = 0; i < 40; ++i) s += cursor[base + i];
  part[t] = s;
  __syncthreads();
  for (int off = 1; off < 1024; off <<= 1){
    u32 v = (t >= off) ? part[t - off] : 0u;
    __syncthreads();
    part[t] += v;
    __syncthreads();
  }
  u32 run = (t == 0) ? 0u : part[t - 1];
  for (int i = 0; i < 40; ++i){
    u32 d = cursor[base + i];
    offs[base + i] = run;
    cursor[base + i] = run;
    run += d;
  }
  if (t == 1023) offs[NN] = run;
}

__global__ void k_scatter(const void* __restrict__ ei, u32* __restrict__ cursor,
                          u32* __restrict__ csr, const int* __restrict__ flags){
  int e = blockIdx.x*256 + threadIdx.x;
  if (e >= ET) return;
  int f = flags[0];
  int s, dd;
  if (e < NE){ s = geti(ei, e, f, NN); dd = geti(ei, (long long)NE + e, f, NN); }
  else { s = dd = e - NE; }
  u32 pos = atomicAdd(&cursor[dd], 1u);
  csr[pos] = (u32)s | ((u32)dd << 16);
}

__global__ void k_bounds(const void* __restrict__ batch, u32* __restrict__ bnd, const int* __restrict__ flags){
  int g = threadIdx.x;
  if (g > NG) return;
  if (g == NG){ bnd[NG] = NN; return; }
  int f = flags[0];
  int lo = 0, hi = NN;
  while (lo < hi){
    int mid = (lo + hi) >> 1;
    if (geti(batch, mid, f, NG) < g) lo = mid + 1; else hi = mid;
  }
  bnd[g] = (u32)lo;
}

// ---------- GEMM: 128 rows x 64 cols per block, BK=64, 8x4 register tile ----------
// Per k: 32 FMA vs 3 LDS b128 -> VALU-dominant. Xs reads are wave-broadcast
// (4 distinct addrs/wave); Ws [64][64] is 2-way both sides; Xs stage-writes
// 2-way via XOR swizzle. LDS 48KB -> 3 blocks/CU.
__global__ __launch_bounds__(256, 3) void k_gemm(const float* __restrict__ X, const float* __restrict__ pr,
                                                 float* __restrict__ xl, float* __restrict__ xr)
{
  __shared__ float Xs[64][128];   // [k][row], row XOR-swizzled
  __shared__ float Ws[64][64];    // [k][col]
  int tid = threadIdx.x;
  int row0 = blockIdx.x * 128;
  int bc0  = blockIdx.y * 64;

  int ty = tid >> 4, tx = tid & 15;
  int r = ty*4, c = tx*4;
  float4 bias = *(const float4*)(pr + 32768 + bc0 + c);
  float acc[8][4];
  #pragma unroll
  for (int i = 0; i < 8; ++i){
    acc[i][0] = bias.x; acc[i][1] = bias.y; acc[i][2] = bias.z; acc[i][3] = bias.w;
  }

  #pragma unroll
  for (int kt = 0; kt < 2; ++kt){
    // stage X: 128 rows x 64 k
    const float* Xb = X + (size_t)row0*D + kt*64;
    #pragma unroll
    for (int i = 0; i < 8; ++i){
      int idx = tid + i*256;
      int row = idx >> 4, k4 = idx & 15;
      float4 v = *(const float4*)(Xb + (size_t)row*D + k4*4);
      int rs = row ^ (k4 << 2);
      Xs[k4*4+0][rs] = v.x;
      Xs[k4*4+1][rs] = v.y;
      Xs[k4*4+2][rs] = v.z;
      Xs[k4*4+3][rs] = v.w;
    }
    // stage W: 64 k x 64 cols
    const float* Wb = pr + (size_t)kt*64*256 + bc0;
    #pragma unroll
    for (int i = 0; i < 4; ++i){
      int idx = tid + i*256;
      int k = idx >> 4, c4 = idx & 15;
      *(float4*)&Ws[k][c4*4] = *(const float4*)(Wb + (size_t)k*256 + c4*4);
    }
    __syncthreads();
    #pragma unroll 4
    for (int k = 0; k < 64; ++k){
      int swb = (k >> 2) << 2;
      float4 a0 = *(const float4*)&Xs[k][(r ^ swb)];
      float4 a1 = *(const float4*)&Xs[k][(r ^ swb) + 64];
      float4 b = *(const float4*)&Ws[k][c];
      acc[0][0] = fmaf(a0.x, b.x, acc[0][0]); acc[0][1] = fmaf(a0.x, b.y, acc[0][1]);
      acc[0][2] = fmaf(a0.x, b.z, acc[0][2]); acc[0][3] = fmaf(a0.x, b.w, acc[0][3]);
      acc[1][0] = fmaf(a0.y, b.x, acc[1][0]); acc[1][1] = fmaf(a0.y, b.y, acc[1][1]);
      acc[1][2] = fmaf(a0.y, b.z, acc[1][2]); acc[1][3] = fmaf(a0.y, b.w, acc[1][3]);
      acc[2][0] = fmaf(a0.z, b.x, acc[2][0]); acc[2][1] = fmaf(a0.z, b.y, acc[2][1]);
      acc[2][2] = fmaf(a0.z, b.z, acc[2][2]); acc[2][3] = fmaf(a0.z, b.w, acc[2][3]);
      acc[3][0] = fmaf(a0.w, b.x, acc[3][0]); acc[3][1] = fmaf(a0.w, b.y, acc[3][1]);
      acc[3][2] = fmaf(a0.w, b.z, acc[3][2]); acc[3][3] = fmaf(a0.w, b.w, acc[3][3]);
      acc[4][0] = fmaf(a1.x, b.x, acc[4][0]); acc[4][1] = fmaf(a1.x, b.y, acc[4][1]);
      acc[4][2] = fmaf(a1.x, b.z, acc[4][2]); acc[4][3] = fmaf(a1.x, b.w, acc[4][3]);
      acc[5][0] = fmaf(a1.y, b.x, acc[5][0]); acc[5][1] = fmaf(a1.y, b.y, acc[5][1]);
      acc[5][2] = fmaf(a1.y, b.z, acc[5][2]); acc[5][3] = fmaf(a1.y, b.w, acc[5][3]);
      acc[6][0] = fmaf(a1.z, b.x, acc[6][0]); acc[6][1] = fmaf(a1.z, b.y, acc[6][1]);
      acc[6][2] = fmaf(a1.z, b.z, acc[6][2]); acc[6][3] = fmaf(a1.z, b.w, acc[6][3]);
      acc[7][0] = fmaf(a1.w, b.x, acc[7][0]); acc[7][1] = fmaf(a1.w, b.y, acc[7][1]);
      acc[7][2] = fmaf(a1.w, b.z, acc[7][2]); acc[7][3] = fmaf(a1.w, b.w, acc[7][3]);
    }
    __syncthreads();
  }

  float* base = (bc0 < 128) ? xl : xr;
  int co = (bc0 < 128) ? bc0 + c : bc0 - 128 + c;
  #pragma unroll
  for (int i = 0; i < 4; ++i){
    *(float4*)(base + (size_t)(row0 + r + i)*D + co) =
        make_float4(acc[i][0], acc[i][1], acc[i][2], acc[i][3]);
    *(float4*)(base + (size_t)(row0 + 64 + r + i)*D + co) =
        make_float4(acc[4+i][0], acc[4+i][1], acc[4+i][2], acc[4+i][3]);
  }
}

// ---------- fused per-node attention: wave/node, 2 edges/iter, defer-max, pipelined gather ----------
__global__ __launch_bounds__(256) void k_node(const float* __restrict__ xl, const float* __restrict__ xr,
    const u32* __restrict__ offs, const u32* __restrict__ csr, const float* __restrict__ pr,
    float* __restrict__ hnew, void* __restrict__ out, const int* __restrict__ flags, int last)
{
  int node = blockIdx.x*4 + (threadIdx.x >> 6);
  int lane = threadIdx.x & 63;
  int half = lane >> 5;
  int c = (lane & 31) * 4;
  float4 xrv  = *(const float4*)(xr + (size_t)node*D + c);
  float4 attv = *(const float4*)(pr + 33024 + c);
  u32 j0 = offs[node], j1 = offs[node + 1];

  float mx = -1e30f, ssum = 0.f;
  float4 acc = make_float4(0.f, 0.f, 0.f, 0.f);

  u32 j = j0 + half;
  float4 g_cur = make_float4(0.f,0.f,0.f,0.f);
  int sn = 0;
  if (j < j1){
    int sc = (int)(csr[j] & 0xFFFFu);
    g_cur = *(const float4*)(xl + (size_t)sc*D + c);
    u32 j2 = j + 2;
    sn = (int)(csr[(j2 < j1) ? j2 : j0] & 0xFFFFu);
  }
  for (; j < j1; j += 2){
    // issue next gather + csr prefetch before touching g_cur
    float4 g_nxt = g_cur;
    if (j + 2 < j1) g_nxt = *(const float4*)(xl + (size_t)sn*D + c);
    u32 j4 = j + 4;
    int s4 = (int)(csr[(j4 < j1) ? j4 : j0] & 0xFFFFu);

    float m, p;
    m = g_cur.x + xrv.x; p = fmaxf(m, 0.2f*m) * attv.x;
    m = g_cur.y + xrv.y; p = fmaf(fmaxf(m, 0.2f*m), attv.y, p);
    m = g_cur.z + xrv.z; p = fmaf(fmaxf(m, 0.2f*m), attv.z, p);
    m = g_cur.w + xrv.w; p = fmaf(fmaxf(m, 0.2f*m), attv.w, p);
    p += __shfl_xor(p, 1, 64);
    p += __shfl_xor(p, 2, 64);
    p += __shfl_xor(p, 4, 64);     // all 8 head-lanes hold the logit
    if (p > mx + 8.f){             // deferred-max rescale (always taken on 1st edge)
      float eo = __expf(mx - p);
      ssum  *= eo;
      acc.x *= eo; acc.y *= eo; acc.z *= eo; acc.w *= eo;
      mx = p;
    }
    float en = __expf(p - mx);     // <= e^8, harmless in f32
    ssum += en;
    acc.x = fmaf(en, g_cur.x, acc.x);
    acc.y = fmaf(en, g_cur.y, acc.y);
    acc.z = fmaf(en, g_cur.z, acc.z);
    acc.w = fmaf(en, g_cur.w, acc.w);

    g_cur = g_nxt; sn = s4;
  }
  // merge the two half-wave states (lanes l and l+32 share channels)
  float mo = __shfl_xor(mx, 32, 64);
  float so = __shfl_xor(ssum, 32, 64);
  float ax = __shfl_xor(acc.x, 32, 64);
  float ay = __shfl_xor(acc.y, 32, 64);
  float az = __shfl_xor(acc.z, 32, 64);
  float aw = __shfl_xor(acc.w, 32, 64);
  float n  = fmaxf(mx, mo);
  float e0 = __expf(mx - n), e1 = __expf(mo - n);
  ssum  = ssum*e0 + so*e1;
  acc.x = acc.x*e0 + ax*e1;
  acc.y = acc.y*e0 + ay*e1;
  acc.z = acc.z*e0 + az*e1;
  acc.w = acc.w*e0 + aw*e1;

  if (half == 0){
    float inv = 1.0f / fmaxf(ssum, 1e-30f);
    float4 bv = *(const float4*)(pr + 33152 + c);
    float4 v = make_float4(acc.x*inv + bv.x, acc.y*inv + bv.y,
                           acc.z*inv + bv.z, acc.w*inv + bv.w);
    if (!last){
      v.x = fmaxf(v.x, 0.f); v.y = fmaxf(v.y, 0.f);
      v.z = fmaxf(v.z, 0.f); v.w = fmaxf(v.w, 0.f);
      *(float4*)(hnew + (size_t)node*D + c) = v;
    } else {
      *(float4*)(hnew + (size_t)node*D + c) = v;
      int isbf = flags[1];
      long long o = (long long)NG*D + (long long)node*D + c;
      stf(out, o+0, v.x, isbf); stf(out, o+1, v.y, isbf);
      stf(out, o+2, v.z, isbf); stf(out, o+3, v.w, isbf);
    }
  }
}

// ---------- two-stage mean pool ----------
__global__ __launch_bounds__(256) void k_pool1(const float* __restrict__ h, const u32* __restrict__ bnd,
                                               float* __restrict__ pool){
  int g = blockIdx.x >> 6, sl = blockIdx.x & 63;
  int ch = threadIdx.x & 127, ro = threadIdx.x >> 7;
  u32 b0 = bnd[g], b1 = bnd[g + 1];
  float acc = 0.f;
  for (u32 r = b0 + sl*2 + ro; r < b1; r += 128) acc += h[(size_t)r*D + ch];
  unsafeAtomicAdd(&pool[g*D + ch], acc);
}

__global__ void k_pool2(const float* __restrict__ pool, const u32* __restrict__ bnd,
                        void* __restrict__ out, const int* __restrict__ flags){
  int i = blockIdx.x*256 + threadIdx.x;
  if (i >= NG*D) return;
  int g = i >> 7;
  float c = (float)(bnd[g + 1] - bnd[g]);
  stf(out, i, pool[i] / fmaxf(c, 1.f), flags[1]);
}

extern "C" void kernel_launch(void* const* d_in, const int* in_sizes, int n_in,
                              void* d_out, int out_size, void* d_ws, size_t ws_size,
                              hipStream_t stream) {
  const void* x     = d_in[0];
  const void* ei    = d_in[1];
  const void* batch = d_in[2];

  const long long nf = (long long)NN*D*3 + 3*PL + NG*D;
  const long long nu = (NN + 1) + NN + ET + (NG + 1) + 2;
  if (ws_size < (size_t)(nf + nu)*4 + 256) return;

  float* ws    = (float*)d_ws;
  float* xf    = ws;                               // NN*D (h buffer each layer)
  float* xl    = xf + (size_t)NN*D;
  float* xr    = xl + (size_t)NN*D;
  float* prm   = xr + (size_t)NN*D;                // 3*PL
  float* pool  = prm + 3*PL;                       // NG*D
  u32*  offs   = (u32*)(pool + NG*D);              // NN+1
  u32*  cursor = offs + (NN + 1);                  // NN
  u32*  csr    = cursor + NN;                      // ET
  u32*  bnd    = csr + ET;                         // NG+1
  int*  flags  = (int*)(bnd + (NG + 1));           // 2

  k_setup<<<169, 256, 0, stream>>>(ei, x, flags, cursor, pool);
  k_cvt<<<(NN*D)/256, 256, 0, stream>>>(x, xf, NN*D, flags);
  P18 ps;
  for (int i = 0; i < 18; ++i) ps.p[i] = d_in[3 + i];
  k_cvtp<<<dim3((PL + 255)/256, 3), 256, 0, stream>>>(ps, prm, flags);

  k_hist<<<ET/256, 256, 0, stream>>>(ei, cursor, flags);
  k_scan<<<1, 1024, 0, stream>>>(cursor, offs);
  k_scatter<<<ET/256, 256, 0, stream>>>(ei, cursor, csr, flags);
  k_bounds<<<1, 32, 0, stream>>>(batch, bnd, flags);

  for (int l = 0; l < 3; ++l){
    const float* p = prm + (size_t)l*PL;
    k_gemm<<<dim3(NN/128, 4), 256, 0, stream>>>(xf, p, xl, xr);
    k_node<<<NN/4, 256, 0, stream>>>(xl, xr, offs, csr, p, xf, d_out, flags, l == 2);
  }
  k_pool1<<<NG*64, 256, 0, stream>>>(xf, bnd, pool);
  k_pool2<<<8, 256, 0, stream>>>(pool, bnd, d_out, flags);
}